// Round 13
// baseline (107.356 us; speedup 1.0000x reference)
//
#include <hip/hip_runtime.h>
#include <stdint.h>

#define Td 1024
#define Hd 1024
#define Id 1024
#define Ed 8
#define Kd 2
#define Ld 4
#define Rd 16
#define Nd 2048
#define TKd (Td*Kd)

typedef __bf16 bf16x8 __attribute__((ext_vector_type(8)));
typedef float f32x4 __attribute__((ext_vector_type(4)));

__device__ __forceinline__ ushort f2bf(float f) {
    uint32_t u = __builtin_bit_cast(uint32_t, f);
    return (ushort)((u + 0x7fffu + ((u >> 16) & 1u)) >> 16);
}
__device__ __forceinline__ float bf2f(ushort u) {
    uint32_t x = ((uint32_t)u) << 16;
    return __builtin_bit_cast(float, x);
}
__device__ __forceinline__ bf16x8 pack8(float4 a, float4 b) {
    bf16x8 r;
    r[0] = (__bf16)a.x; r[1] = (__bf16)a.y; r[2] = (__bf16)a.z; r[3] = (__bf16)a.w;
    r[4] = (__bf16)b.x; r[5] = (__bf16)b.y; r[6] = (__bf16)b.z; r[7] = (__bf16)b.w;
    return r;
}
// 16 consecutive fp32 -> 16 bf16
__device__ __forceinline__ void cvt16(const float* __restrict__ s, ushort* __restrict__ d) {
    float4 a0 = *(const float4*)(s);
    float4 a1 = *(const float4*)(s + 4);
    float4 a2 = *(const float4*)(s + 8);
    float4 a3 = *(const float4*)(s + 12);
    uint4 o0, o1;
    o0.x = (uint)f2bf(a0.x) | ((uint)f2bf(a0.y) << 16);
    o0.y = (uint)f2bf(a0.z) | ((uint)f2bf(a0.w) << 16);
    o0.z = (uint)f2bf(a1.x) | ((uint)f2bf(a1.y) << 16);
    o0.w = (uint)f2bf(a1.z) | ((uint)f2bf(a1.w) << 16);
    o1.x = (uint)f2bf(a2.x) | ((uint)f2bf(a2.y) << 16);
    o1.y = (uint)f2bf(a2.z) | ((uint)f2bf(a2.w) << 16);
    o1.z = (uint)f2bf(a3.x) | ((uint)f2bf(a3.y) << 16);
    o1.w = (uint)f2bf(a3.z) | ((uint)f2bf(a3.w) << 16);
    *(uint4*)(d) = o0;
    *(uint4*)(d + 8) = o1;
}

#define GLOAD_LDS16(g, l) __builtin_amdgcn_global_load_lds( \
    (const __attribute__((address_space(1))) uint32_t*)(const void*)(g), \
    (__attribute__((address_space(3))) uint32_t*)(void*)(l), 16, 0, 0)

// block-role partition of k_prep: w2 convert + LoRA-A proj + x convert + interleave + zero + route
#define W2C 2048
#define TB 2048
#define XB 256
#define CB 384
#define ZB 1024
#define PREP_BLOCKS (W2C + TB + XB + CB + ZB + 1)

__global__ __launch_bounds__(256) void k_prep(
    const float* __restrict__ hid, const float* __restrict__ w2,
    const float* __restrict__ gb, const float* __restrict__ db,
    const float* __restrict__ ga, const float* __restrict__ sc,
    const int* __restrict__ tids, const int* __restrict__ lidx,
    ushort* __restrict__ xb, ushort* __restrict__ w2b,
    ushort* __restrict__ gbbe, ushort* __restrict__ dbbe, ushort* __restrict__ tmp1e,
    float* __restrict__ out, int* __restrict__ sorted, int* __restrict__ offs)
{
    __shared__ float tr[Rd];
    __shared__ int cnt[Ed];
    __shared__ int cur[Ed];
    const int b = blockIdx.x, tid = threadIdx.x;

    if (b < W2C) {
        size_t off = ((size_t)b * 256 + tid) * 16;
        cvt16(w2 + off, w2b + off);
    } else if (b < W2C + TB) {
        const int p = b - W2C;
        const int e = tids[p];
        const int l = lidx[p >> 1];
        const float s = sc[l];
        const int r = tid >> 4, q = tid & 15;
        const float* A = ga + (((size_t)l * Ed + e) * Rd + r) * 1024;
        const float* x = hid + (size_t)(p >> 1) * 1024;
        float sum = 0.f;
        #pragma unroll
        for (int i = 0; i < 16; ++i) {
            int h = q * 4 + 64 * i;
            float4 a = *(const float4*)(A + h);
            float4 v = *(const float4*)(x + h);
            sum += a.x * v.x + a.y * v.y + a.z * v.z + a.w * v.w;
        }
        sum += __shfl_xor(sum, 1); sum += __shfl_xor(sum, 2);
        sum += __shfl_xor(sum, 4); sum += __shfl_xor(sum, 8);
        if (q == 0) tr[r] = sum;
        __syncthreads();
        if (tid < 32) {
            int j0 = tid * 2;
            uint v = 0;
            if ((j0 >> 4) == l)
                v = (uint)f2bf(s * tr[j0 & 15]) | ((uint)f2bf(s * tr[(j0 + 1) & 15]) << 16);
            ((uint*)(tmp1e + (size_t)p * 64))[tid] = v;
        }
    } else if (b < W2C + TB + XB) {
        size_t off = ((size_t)(b - W2C - TB) * 256 + tid) * 16;
        cvt16(hid + off, xb + off);
    } else if (b < W2C + TB + XB + CB) {
        constexpr int GR = Ld * Ed * Nd;
        int i = (b - W2C - TB - XB) * 256 + tid;
        const float* src; ushort* dst;
        if (i < GR) {
            int l = i >> 14, e = (i >> 11) & 7, n = i & 2047;
            src = gb + (size_t)i * 16;
            dst = gbbe + ((size_t)(e * Nd + n)) * 64 + l * 16;
        } else {
            int j = i - GR;
            int l = j >> 13, e = (j >> 10) & 7, n = j & 1023;
            src = db + (size_t)j * 16;
            dst = dbbe + ((size_t)(e * Id + n)) * 64 + l * 16;
        }
        cvt16(src, dst);
    } else if (b < W2C + TB + XB + CB + ZB) {
        int i = (b - W2C - TB - XB - CB) * 256 + tid;
        ((float4*)out)[i] = make_float4(0.f, 0.f, 0.f, 0.f);
    } else {
        if (tid < Ed) cnt[tid] = 0;
        __syncthreads();
        int el[8];
        #pragma unroll
        for (int i = 0; i < 8; ++i) {
            el[i] = tids[tid + i * 256];
            atomicAdd(&cnt[el[i]], 1);
        }
        __syncthreads();
        if (tid == 0) {
            int s = 0;
            for (int e = 0; e < Ed; ++e) { offs[e] = s; cur[e] = s; s += cnt[e]; }
            offs[Ed] = s;
        }
        __syncthreads();
        #pragma unroll
        for (int i = 0; i < 8; ++i) {
            int pos = atomicAdd(&cur[el[i]], 1);
            sorted[pos] = tid + i * 256;
        }
    }
}

// ---------------- down LoRA-A projection (act bf16 input) ----------------
__global__ __launch_bounds__(256) void k_tmp_dn(
    const ushort* __restrict__ act, const float* __restrict__ da,
    const float* __restrict__ sc, const int* __restrict__ tids,
    const int* __restrict__ lidx, ushort* __restrict__ tmpde)
{
    const int p = blockIdx.x;
    const int e = tids[p];
    const int l = lidx[p >> 1];
    const float s = sc[l];
    const int tid = threadIdx.x;
    const int r = tid >> 4, q = tid & 15;
    const float* A = da + (((size_t)l * Ed + e) * Rd + r) * 1024;
    const ushort* x = act + (size_t)p * 1024;
    float sum = 0.f;
    #pragma unroll
    for (int i = 0; i < 8; ++i) {
        int h = q * 8 + 128 * i;
        float4 a0 = *(const float4*)(A + h);
        float4 a1 = *(const float4*)(A + h + 4);
        ushort4 v0 = *(const ushort4*)(x + h);
        ushort4 v1 = *(const ushort4*)(x + h + 4);
        sum += a0.x * bf2f(v0.x) + a0.y * bf2f(v0.y) + a0.z * bf2f(v0.z) + a0.w * bf2f(v0.w)
             + a1.x * bf2f(v1.x) + a1.y * bf2f(v1.y) + a1.z * bf2f(v1.z) + a1.w * bf2f(v1.w);
    }
    sum += __shfl_xor(sum, 1); sum += __shfl_xor(sum, 2);
    sum += __shfl_xor(sum, 4); sum += __shfl_xor(sum, 8);
    __shared__ float tr[Rd];
    if (q == 0) tr[r] = sum;
    __syncthreads();
    if (tid < 32) {
        int j0 = tid * 2;
        uint v = 0;
        if ((j0 >> 4) == l)
            v = (uint)f2bf(s * tr[j0 & 15]) | ((uint)f2bf(s * tr[(j0 + 1) & 15]) << 16);
        ((uint*)(tmpde + (size_t)p * 64))[tid] = v;
    }
}

// ---------------- gate_up GEMM: ring-3 LDS, counted vmcnt + sched_barrier fences ----------------
__global__ __launch_bounds__(256) void k_gemm_gu(
    const ushort* __restrict__ xb, const float* __restrict__ w13,
    const ushort* __restrict__ tmp1e, const ushort* __restrict__ gbbe,
    ushort* __restrict__ act, const int* __restrict__ sorted,
    const int* __restrict__ offs)
{
    __shared__ ushort As[3][64][32];
    __shared__ ushort Bs[3][128][32];
    const int tid = threadIdx.x, lane = tid & 63, wave = tid >> 6;
    const int wr = wave >> 1, wc = wave & 1;
    const int fr = lane & 15, fk = (lane >> 4) * 8;

    int off[Ed + 1];
    #pragma unroll
    for (int e = 0; e <= Ed; ++e) off[e] = offs[e];
    int mt[Ed]; int tot = 0;
    #pragma unroll
    for (int e = 0; e < Ed; ++e) {
        mt[e] = (off[e + 1] - off[e] + 63) / 64;
        tot += mt[e] * 16;
    }

    for (int tau = blockIdx.x; tau < tot; tau += gridDim.x) {
        int t = tau, e = 0;
        while (t >= mt[e] * 16) { t -= mt[e] * 16; ++e; }
        const int m0 = off[e] + (t >> 4) * 64;
        const int mend = off[e + 1];
        const int n0 = (t & 15) * 64;

        const ushort *asrc, *aesrc;
        {
            int aIdx = m0 + (tid >> 2); if (aIdx > mend - 1) aIdx = mend - 1;
            int p = sorted[aIdx];
            asrc  = xb + (size_t)(p >> 1) * 1024 + (tid & 3) * 8;
            aesrc = tmp1e + (size_t)p * 64 + (tid & 3) * 8;
        }
        const int brow = tid >> 1, bhalf = tid & 1;
        const int bg_row = (brow < 64) ? (n0 + brow) : (1024 + n0 + brow - 64);
        const float* bsrc = w13 + ((size_t)e * Nd + bg_row) * 1024 + bhalf * 16;
        const ushort* besrc[2];
        #pragma unroll
        for (int r = 0; r < 2; ++r) {
            int c = r * 256 + tid;
            int row = c >> 2, kc = c & 3;
            int grow = (row < 64) ? (n0 + row) : (1024 + n0 + row - 64);
            besrc[r] = gbbe + ((size_t)e * Nd + grow) * 64 + kc * 8;
        }

        f32x4 ag[2][2] = {}, au[2][2] = {};
        float4 Y0[4], Y1[4];

        auto issueA = [&](int s, int b) {
            GLOAD_LDS16(asrc + s * 32, (char*)&As[b][0][0] + (wave * 64) * 16);
        };
        auto loadB = [&](int s, float4* Y) {
            const float* p = bsrc + s * 32;
            Y[0] = *(const float4*)(p);
            Y[1] = *(const float4*)(p + 4);
            Y[2] = *(const float4*)(p + 8);
            Y[3] = *(const float4*)(p + 12);
        };
        auto writeB = [&](float4* Y, int b) {
            *(bf16x8*)(&Bs[b][brow][bhalf * 16])     = pack8(Y[0], Y[1]);
            *(bf16x8*)(&Bs[b][brow][bhalf * 16 + 8]) = pack8(Y[2], Y[3]);
        };
        auto step = [&](int b) {
            bf16x8 af[2], bg[2], bu[2];
            #pragma unroll
            for (int mi = 0; mi < 2; ++mi)
                af[mi] = *(const bf16x8*)(&As[b][wr * 32 + mi * 16 + fr][fk]);
            #pragma unroll
            for (int ni = 0; ni < 2; ++ni) {
                bg[ni] = *(const bf16x8*)(&Bs[b][wc * 32 + ni * 16 + fr][fk]);
                bu[ni] = *(const bf16x8*)(&Bs[b][64 + wc * 32 + ni * 16 + fr][fk]);
            }
            #pragma unroll
            for (int mi = 0; mi < 2; ++mi)
                #pragma unroll
                for (int ni = 0; ni < 2; ++ni) {
                    ag[mi][ni] = __builtin_amdgcn_mfma_f32_16x16x32_bf16(af[mi], bg[ni], ag[mi][ni], 0, 0, 0);
                    au[mi][ni] = __builtin_amdgcn_mfma_f32_16x16x32_bf16(af[mi], bu[ni], au[mi][ni], 0, 0, 0);
                }
        };

        // prologue: stage 0,1 issued; stage0's B written once arrived
        issueA(0, 0); loadB(0, Y0);
        issueA(1, 1); loadB(1, Y1);
        asm volatile("s_waitcnt vmcnt(5)" ::: "memory");    // stage0 arrived (stage1 in flight)
        writeB(Y0, 0);

        int b0 = 0;
        for (int s = 0; s < 32; s += 2) {
            int b1 = b0 + 1; if (b1 == 3) b1 = 0;
            int b2 = b1 + 1; if (b2 == 3) b2 = 0;
            // ---- even body: compute stage s, issue s+2, retire s+1's B ----
            asm volatile("s_waitcnt vmcnt(5) lgkmcnt(0)" ::: "memory");
            __builtin_amdgcn_s_barrier();
            __builtin_amdgcn_sched_barrier(0);   // pin LDS reads AFTER the barrier
            if (s + 2 < 32) { issueA(s + 2, b2); loadB(s + 2, Y0); }
            step(b0);
            if (s + 2 < 32) asm volatile("s_waitcnt vmcnt(5)" ::: "memory");
            else            asm volatile("s_waitcnt vmcnt(0)" ::: "memory");
            writeB(Y1, b1);                                  // stage s+1 B
            // ---- odd body: compute stage s+1, issue s+3, retire s+2's B ----
            asm volatile("s_waitcnt vmcnt(5) lgkmcnt(0)" ::: "memory");
            __builtin_amdgcn_s_barrier();
            __builtin_amdgcn_sched_barrier(0);   // pin LDS reads AFTER the barrier
            if (s + 3 < 32) { issueA(s + 3, b0); loadB(s + 3, Y1); }
            step(b1);
            if (s + 2 < 32) {
                if (s + 3 < 32) asm volatile("s_waitcnt vmcnt(5)" ::: "memory");
                else            asm volatile("s_waitcnt vmcnt(0)" ::: "memory");
                writeB(Y0, b2);                              // stage s+2 B
            }
            b0 = b2;
        }

        // drain, then LoRA-ext K-steps classic
        asm volatile("s_waitcnt vmcnt(0) lgkmcnt(0)" ::: "memory");
        __syncthreads();
        #pragma unroll
        for (int es = 0; es < 2; ++es) {
            GLOAD_LDS16(aesrc + es * 32, (char*)&As[es][0][0] + (wave * 64) * 16);
            #pragma unroll
            for (int r = 0; r < 2; ++r)
                GLOAD_LDS16(besrc[r] + es * 32, (char*)&Bs[es][0][0] + (r * 256 + wave * 64) * 16);
            __syncthreads();
            step(es);
            __syncthreads();
        }

        // epilogue: fused silu_and_mul -> act bf16
        const int rb = wr * 32 + (lane >> 4) * 4;
        #pragma unroll
        for (int mi = 0; mi < 2; ++mi) {
            #pragma unroll
            for (int j = 0; j < 4; ++j) {
                int sidx = m0 + rb + mi * 16 + j;
                if (sidx < mend) {
                    int p = sorted[sidx];
                    ushort* ar = act + (size_t)p * 1024 + n0 + wc * 32;
                    #pragma unroll
                    for (int ni = 0; ni < 2; ++ni) {
                        float g = ag[mi][ni][j], u = au[mi][ni][j];
                        float v = g / (1.f + __expf(-g)) * u;
                        ar[ni * 16 + fr] = f2bf(v);
                    }
                }
            }
        }
        __syncthreads();
    }
}

// ---------------- down GEMM (R11 proven): BM=64, BN=64, all-bf16 single-buffer ----------------
__global__ __launch_bounds__(256) void k_gemm_dn(
    const ushort* __restrict__ act, const ushort* __restrict__ w2b,
    const ushort* __restrict__ tmpde, const ushort* __restrict__ dbbe,
    const float* __restrict__ tw, float* __restrict__ out,
    const int* __restrict__ sorted, const int* __restrict__ offs)
{
    __shared__ ushort As[64][32];
    __shared__ ushort Bs[64][32];
    const int tid = threadIdx.x, lane = tid & 63, wave = tid >> 6;
    const int wr = wave >> 1, wc = wave & 1;
    const int fr = lane & 15, fk = (lane >> 4) * 8;

    int off[Ed + 1];
    #pragma unroll
    for (int e = 0; e <= Ed; ++e) off[e] = offs[e];
    int mt[Ed]; int tot = 0;
    #pragma unroll
    for (int e = 0; e < Ed; ++e) {
        mt[e] = (off[e + 1] - off[e] + 63) / 64;
        tot += mt[e] * 16;
    }

    for (int tau = blockIdx.x; tau < tot; tau += gridDim.x) {
        int t = tau, e = 0;
        while (t >= mt[e] * 16) { t -= mt[e] * 16; ++e; }
        const int m0 = off[e] + (t >> 4) * 64;
        const int mend = off[e + 1];
        const int n0 = (t & 15) * 64;

        const ushort *asrc, *aesrc, *bsrc, *besrc;
        {
            int aIdx = m0 + (tid >> 2); if (aIdx > mend - 1) aIdx = mend - 1;
            int p = sorted[aIdx];
            asrc  = act + (size_t)p * 1024 + (tid & 3) * 8;
            aesrc = tmpde + (size_t)p * 64 + (tid & 3) * 8;
            int row = tid >> 2, kc = tid & 3;
            bsrc  = w2b + ((size_t)e * Hd + n0 + row) * 1024 + kc * 8;
            besrc = dbbe + ((size_t)e * Hd + n0 + row) * 64 + kc * 8;
        }

        f32x4 acc[2][2] = {};
        auto step = [&]() {
            bf16x8 af[2], bv[2];
            #pragma unroll
            for (int mi = 0; mi < 2; ++mi)
                af[mi] = *(const bf16x8*)(&As[wr * 32 + mi * 16 + fr][fk]);
            #pragma unroll
            for (int ni = 0; ni < 2; ++ni)
                bv[ni] = *(const bf16x8*)(&Bs[wc * 32 + ni * 16 + fr][fk]);
            #pragma unroll
            for (int mi = 0; mi < 2; ++mi)
                #pragma unroll
                for (int ni = 0; ni < 2; ++ni)
                    acc[mi][ni] = __builtin_amdgcn_mfma_f32_16x16x32_bf16(af[mi], bv[ni], acc[mi][ni], 0, 0, 0);
        };

        for (int k0 = 0; k0 < 1024; k0 += 32) {
            GLOAD_LDS16(asrc + k0, (char*)&As[0][0] + (wave * 64) * 16);
            GLOAD_LDS16(bsrc + k0, (char*)&Bs[0][0] + (wave * 64) * 16);
            __syncthreads();
            step();
            __syncthreads();
        }
        #pragma unroll
        for (int es = 0; es < 2; ++es) {
            GLOAD_LDS16(aesrc + es * 32, (char*)&As[0][0] + (wave * 64) * 16);
            GLOAD_LDS16(besrc + es * 32, (char*)&Bs[0][0] + (wave * 64) * 16);
            __syncthreads();
            step();
            __syncthreads();
        }

        const int rb = wr * 32 + (lane >> 4) * 4;
        #pragma unroll
        for (int mi = 0; mi < 2; ++mi) {
            #pragma unroll
            for (int j = 0; j < 4; ++j) {
                int sidx = m0 + rb + mi * 16 + j;
                if (sidx < mend) {
                    int p = sorted[sidx];
                    float w = tw[p];
                    float* orow = out + (size_t)(p >> 1) * 1024 + n0 + wc * 32;
                    #pragma unroll
                    for (int ni = 0; ni < 2; ++ni)
                        atomicAdd(&orow[ni * 16 + fr], w * acc[mi][ni][j]);
                }
            }
        }
    }
}

extern "C" void kernel_launch(void* const* d_in, const int* in_sizes, int n_in,
                              void* d_out, int out_size, void* d_ws, size_t ws_size,
                              hipStream_t stream) {
    const float* hid  = (const float*)d_in[0];
    const float* tw   = (const float*)d_in[1];
    const float* w13  = (const float*)d_in[2];
    const float* w2   = (const float*)d_in[3];
    const float* ga   = (const float*)d_in[4];
    const float* gb   = (const float*)d_in[5];
    const float* da   = (const float*)d_in[6];
    const float* db   = (const float*)d_in[7];
    const float* sc   = (const float*)d_in[8];
    const int*   tids = (const int*)d_in[9];
    const int*   lidx = (const int*)d_in[10];
    float* out = (float*)d_out;

    char* ws = (char*)d_ws;
    ushort* xb     = (ushort*)(ws);                          // 2 MB
    ushort* w2b    = (ushort*)(ws + (2ull  << 20));          // 16 MB
    ushort* gbbe   = (ushort*)(ws + (18ull << 20));          // 2 MB
    ushort* dbbe   = (ushort*)(ws + (20ull << 20));          // 1 MB
    ushort* tmp1e  = (ushort*)(ws + (21ull << 20));          // 256 KB
    ushort* tmpde  = (ushort*)(ws + (21ull << 20) + (256u << 10)); // 256 KB
    ushort* act    = (ushort*)(ws + (22ull << 20));          // 4 MB
    int*    sorted = (int*)(ws + (26ull << 20));             // 8 KB
    int*    offs   = (int*)(ws + (26ull << 20) + TKd * 4);   // 36 B

    k_prep<<<PREP_BLOCKS, 256, 0, stream>>>(hid, w2, gb, db, ga, sc, tids, lidx,
                                            xb, w2b, gbbe, dbbe, tmp1e, out, sorted, offs);
    k_gemm_gu<<<1024, 256, 0, stream>>>(xb, w13, tmp1e, gbbe, act, sorted, offs);
    k_tmp_dn<<<TKd, 256, 0, stream>>>(act, da, sc, tids, lidx, tmpde);
    k_gemm_dn<<<1024, 256, 0, stream>>>(act, w2b, tmpde, dbbe, tw, out, sorted, offs);
}

// Round 14
// 89.812 us; speedup vs baseline: 1.1953x; 1.1953x over previous
//
#include <hip/hip_runtime.h>
#include <stdint.h>

#define Td 1024
#define Hd 1024
#define Id 1024
#define Ed 8
#define Kd 2
#define Ld 4
#define Rd 16
#define Nd 2048
#define TKd (Td*Kd)

typedef __bf16 bf16x8 __attribute__((ext_vector_type(8)));
typedef float f32x4 __attribute__((ext_vector_type(4)));

__device__ __forceinline__ ushort f2bf(float f) {
    uint32_t u = __builtin_bit_cast(uint32_t, f);
    return (ushort)((u + 0x7fffu + ((u >> 16) & 1u)) >> 16);
}
__device__ __forceinline__ float bf2f(ushort u) {
    uint32_t x = ((uint32_t)u) << 16;
    return __builtin_bit_cast(float, x);
}
__device__ __forceinline__ bf16x8 pack8(float4 a, float4 b) {
    bf16x8 r;
    r[0] = (__bf16)a.x; r[1] = (__bf16)a.y; r[2] = (__bf16)a.z; r[3] = (__bf16)a.w;
    r[4] = (__bf16)b.x; r[5] = (__bf16)b.y; r[6] = (__bf16)b.z; r[7] = (__bf16)b.w;
    return r;
}
// 16 consecutive fp32 -> 16 bf16
__device__ __forceinline__ void cvt16(const float* __restrict__ s, ushort* __restrict__ d) {
    float4 a0 = *(const float4*)(s);
    float4 a1 = *(const float4*)(s + 4);
    float4 a2 = *(const float4*)(s + 8);
    float4 a3 = *(const float4*)(s + 12);
    uint4 o0, o1;
    o0.x = (uint)f2bf(a0.x) | ((uint)f2bf(a0.y) << 16);
    o0.y = (uint)f2bf(a0.z) | ((uint)f2bf(a0.w) << 16);
    o0.z = (uint)f2bf(a1.x) | ((uint)f2bf(a1.y) << 16);
    o0.w = (uint)f2bf(a1.z) | ((uint)f2bf(a1.w) << 16);
    o1.x = (uint)f2bf(a2.x) | ((uint)f2bf(a2.y) << 16);
    o1.y = (uint)f2bf(a2.z) | ((uint)f2bf(a2.w) << 16);
    o1.z = (uint)f2bf(a3.x) | ((uint)f2bf(a3.y) << 16);
    o1.w = (uint)f2bf(a3.z) | ((uint)f2bf(a3.w) << 16);
    *(uint4*)(d) = o0;
    *(uint4*)(d + 8) = o1;
}

#define GLOAD_LDS16(g, l) __builtin_amdgcn_global_load_lds( \
    (const __attribute__((address_space(1))) uint32_t*)(const void*)(g), \
    (__attribute__((address_space(3))) uint32_t*)(void*)(l), 16, 0, 0)

// block-role partition of k_prep (w2 conversion rides inside k_gemm_gu)
#define TB 2048    // gate_up LoRA-A projection (one per pair)
#define XB 256     // x convert, 16 floats/thread
#define CB 384     // LoRA-B interleave (rows of 16)
#define ZB 1024    // out zeroing
#define PREP_BLOCKS (TB + XB + CB + ZB + 1)

__global__ __launch_bounds__(256) void k_prep(
    const float* __restrict__ hid,
    const float* __restrict__ gb, const float* __restrict__ db,
    const float* __restrict__ ga, const float* __restrict__ sc,
    const int* __restrict__ tids, const int* __restrict__ lidx,
    ushort* __restrict__ xb,
    ushort* __restrict__ gbbe, ushort* __restrict__ dbbe, ushort* __restrict__ tmp1e,
    float* __restrict__ out, int* __restrict__ sorted, int* __restrict__ offs)
{
    __shared__ float tr[Rd];
    __shared__ int cnt[Ed];
    __shared__ int cur[Ed];
    const int b = blockIdx.x, tid = threadIdx.x;

    if (b < TB) {
        // gate_up LoRA-A projection: tmp1e[p][l*16+r] = s*(Ag[l,e]@x[t])
        const int p = b;
        const int e = tids[p];
        const int l = lidx[p >> 1];
        const float s = sc[l];
        const int r = tid >> 4, q = tid & 15;
        const float* A = ga + (((size_t)l * Ed + e) * Rd + r) * 1024;
        const float* x = hid + (size_t)(p >> 1) * 1024;
        float sum = 0.f;
        #pragma unroll
        for (int i = 0; i < 16; ++i) {
            int h = q * 4 + 64 * i;
            float4 a = *(const float4*)(A + h);
            float4 v = *(const float4*)(x + h);
            sum += a.x * v.x + a.y * v.y + a.z * v.z + a.w * v.w;
        }
        sum += __shfl_xor(sum, 1); sum += __shfl_xor(sum, 2);
        sum += __shfl_xor(sum, 4); sum += __shfl_xor(sum, 8);
        if (q == 0) tr[r] = sum;
        __syncthreads();
        if (tid < 32) {
            int j0 = tid * 2;
            uint v = 0;
            if ((j0 >> 4) == l)
                v = (uint)f2bf(s * tr[j0 & 15]) | ((uint)f2bf(s * tr[(j0 + 1) & 15]) << 16);
            ((uint*)(tmp1e + (size_t)p * 64))[tid] = v;
        }
    } else if (b < TB + XB) {
        size_t off = ((size_t)(b - TB) * 256 + tid) * 16;
        cvt16(hid + off, xb + off);
    } else if (b < TB + XB + CB) {
        // LoRA-B l-interleave: gbbe[e][n][l*16+r] = gb[l][e][n][r] (same for db)
        constexpr int GR = Ld * Ed * Nd;
        int i = (b - TB - XB) * 256 + tid;
        const float* src; ushort* dst;
        if (i < GR) {
            int l = i >> 14, e = (i >> 11) & 7, n = i & 2047;
            src = gb + (size_t)i * 16;
            dst = gbbe + ((size_t)(e * Nd + n)) * 64 + l * 16;
        } else {
            int j = i - GR;
            int l = j >> 13, e = (j >> 10) & 7, n = j & 1023;
            src = db + (size_t)j * 16;
            dst = dbbe + ((size_t)(e * Id + n)) * 64 + l * 16;
        }
        cvt16(src, dst);
    } else if (b < TB + XB + CB + ZB) {
        int i = (b - TB - XB - CB) * 256 + tid;
        ((float4*)out)[i] = make_float4(0.f, 0.f, 0.f, 0.f);
    } else {
        // route sort (single block, 8 pairs/thread)
        if (tid < Ed) cnt[tid] = 0;
        __syncthreads();
        int el[8];
        #pragma unroll
        for (int i = 0; i < 8; ++i) {
            el[i] = tids[tid + i * 256];
            atomicAdd(&cnt[el[i]], 1);
        }
        __syncthreads();
        if (tid == 0) {
            int s = 0;
            for (int e = 0; e < Ed; ++e) { offs[e] = s; cur[e] = s; s += cnt[e]; }
            offs[Ed] = s;
        }
        __syncthreads();
        #pragma unroll
        for (int i = 0; i < 8; ++i) {
            int pos = atomicAdd(&cur[el[i]], 1);
            sorted[pos] = tid + i * 256;
        }
    }
}

// ---------------- down LoRA-A projection (act bf16 input) ----------------
__global__ __launch_bounds__(256) void k_tmp_dn(
    const ushort* __restrict__ act, const float* __restrict__ da,
    const float* __restrict__ sc, const int* __restrict__ tids,
    const int* __restrict__ lidx, ushort* __restrict__ tmpde)
{
    const int p = blockIdx.x;
    const int e = tids[p];
    const int l = lidx[p >> 1];
    const float s = sc[l];
    const int tid = threadIdx.x;
    const int r = tid >> 4, q = tid & 15;
    const float* A = da + (((size_t)l * Ed + e) * Rd + r) * 1024;
    const ushort* x = act + (size_t)p * 1024;
    float sum = 0.f;
    #pragma unroll
    for (int i = 0; i < 8; ++i) {
        int h = q * 8 + 128 * i;
        float4 a0 = *(const float4*)(A + h);
        float4 a1 = *(const float4*)(A + h + 4);
        ushort4 v0 = *(const ushort4*)(x + h);
        ushort4 v1 = *(const ushort4*)(x + h + 4);
        sum += a0.x * bf2f(v0.x) + a0.y * bf2f(v0.y) + a0.z * bf2f(v0.z) + a0.w * bf2f(v0.w)
             + a1.x * bf2f(v1.x) + a1.y * bf2f(v1.y) + a1.z * bf2f(v1.z) + a1.w * bf2f(v1.w);
    }
    sum += __shfl_xor(sum, 1); sum += __shfl_xor(sum, 2);
    sum += __shfl_xor(sum, 4); sum += __shfl_xor(sum, 8);
    __shared__ float tr[Rd];
    if (q == 0) tr[r] = sum;
    __syncthreads();
    if (tid < 32) {
        int j0 = tid * 2;
        uint v = 0;
        if ((j0 >> 4) == l)
            v = (uint)f2bf(s * tr[j0 & 15]) | ((uint)f2bf(s * tr[(j0 + 1) & 15]) << 16);
        ((uint*)(tmpde + (size_t)p * 64))[tid] = v;
    }
}

// ---------------- gate_up GEMM (R11): BM=64, A bf16 gload_lds, B w13 fp32 reg-staged dbuf
// ---------------- + w2-convert rider blocks (blockIdx >= GUB) ----------------
#define GUB 1024
#define W2C 2048

__global__ __launch_bounds__(256) void k_gemm_gu(
    const ushort* __restrict__ xb, const float* __restrict__ w13,
    const ushort* __restrict__ tmp1e, const ushort* __restrict__ gbbe,
    const float* __restrict__ w2, ushort* __restrict__ w2b,
    ushort* __restrict__ act, const int* __restrict__ sorted,
    const int* __restrict__ offs)
{
    __shared__ ushort As[2][64][32];
    __shared__ ushort Bs[2][128][32];
    const int tid = threadIdx.x;

    if (blockIdx.x >= GUB) {
        // rider: w2 fp32 -> bf16 (overlaps GEMM; consumed only by k_gemm_dn)
        size_t off = ((size_t)(blockIdx.x - GUB) * 256 + tid) * 16;
        cvt16(w2 + off, w2b + off);
        return;
    }

    const int lane = tid & 63, wave = tid >> 6;
    const int wr = wave >> 1, wc = wave & 1;
    const int fr = lane & 15, fk = (lane >> 4) * 8;

    int off[Ed + 1];
    #pragma unroll
    for (int e = 0; e <= Ed; ++e) off[e] = offs[e];
    int mt[Ed]; int tot = 0;
    #pragma unroll
    for (int e = 0; e < Ed; ++e) {
        mt[e] = (off[e + 1] - off[e] + 63) / 64;
        tot += mt[e] * 16;
    }

    for (int tau = blockIdx.x; tau < tot; tau += GUB) {
        int t = tau, e = 0;
        while (t >= mt[e] * 16) { t -= mt[e] * 16; ++e; }
        const int m0 = off[e] + (t >> 4) * 64;
        const int mend = off[e + 1];
        const int n0 = (t & 15) * 64;

        // A (bf16, 1 round): chunk tid -> row tid>>2, kchunk tid&3
        const ushort *asrc, *aesrc;
        {
            int aIdx = m0 + (tid >> 2); if (aIdx > mend - 1) aIdx = mend - 1;
            int p = sorted[aIdx];
            asrc  = xb + (size_t)(p >> 1) * 1024 + (tid & 3) * 8;
            aesrc = tmp1e + (size_t)p * 64 + (tid & 3) * 8;
        }
        // B fp32: brow = tid>>1 (gate 0-63 / up 64-127), 16 floats per thread
        const int brow = tid >> 1, bhalf = tid & 1;
        const int bg_row = (brow < 64) ? (n0 + brow) : (1024 + n0 + brow - 64);
        const float* bsrc = w13 + ((size_t)e * Nd + bg_row) * 1024 + bhalf * 16;
        // B-ext (bf16, 2 rounds): chunk c -> row c>>2, kchunk c&3
        const ushort* besrc[2];
        #pragma unroll
        for (int r = 0; r < 2; ++r) {
            int c = r * 256 + tid;
            int row = c >> 2, kc = c & 3;
            int grow = (row < 64) ? (n0 + row) : (1024 + n0 + row - 64);
            besrc[r] = gbbe + ((size_t)e * Nd + grow) * 64 + kc * 8;
        }

        f32x4 ag[2][2] = {}, au[2][2] = {};
        auto step = [&](int b) {
            bf16x8 af[2], bg[2], bu[2];
            #pragma unroll
            for (int mi = 0; mi < 2; ++mi)
                af[mi] = *(const bf16x8*)(&As[b][wr * 32 + mi * 16 + fr][fk]);
            #pragma unroll
            for (int ni = 0; ni < 2; ++ni) {
                bg[ni] = *(const bf16x8*)(&Bs[b][wc * 32 + ni * 16 + fr][fk]);
                bu[ni] = *(const bf16x8*)(&Bs[b][64 + wc * 32 + ni * 16 + fr][fk]);
            }
            #pragma unroll
            for (int mi = 0; mi < 2; ++mi)
                #pragma unroll
                for (int ni = 0; ni < 2; ++ni) {
                    ag[mi][ni] = __builtin_amdgcn_mfma_f32_16x16x32_bf16(af[mi], bg[ni], ag[mi][ni], 0, 0, 0);
                    au[mi][ni] = __builtin_amdgcn_mfma_f32_16x16x32_bf16(af[mi], bu[ni], au[mi][ni], 0, 0, 0);
                }
        };

        // prologue: stage k0=0 into buffer 0
        GLOAD_LDS16(asrc, (char*)&As[0][0][0] + (wave * 64) * 16);
        {
            float4 y0 = *(const float4*)(bsrc);
            float4 y1 = *(const float4*)(bsrc + 4);
            float4 y2 = *(const float4*)(bsrc + 8);
            float4 y3 = *(const float4*)(bsrc + 12);
            *(bf16x8*)(&Bs[0][brow][bhalf * 16])     = pack8(y0, y1);
            *(bf16x8*)(&Bs[0][brow][bhalf * 16 + 8]) = pack8(y2, y3);
        }
        __syncthreads();

        int buf = 0;
        for (int k0 = 32; k0 < 1024; k0 += 32) {
            // issue next-step loads first (hide under MFMA)
            GLOAD_LDS16(asrc + k0, (char*)&As[buf ^ 1][0][0] + (wave * 64) * 16);
            float4 y0 = *(const float4*)(bsrc + k0);
            float4 y1 = *(const float4*)(bsrc + k0 + 4);
            float4 y2 = *(const float4*)(bsrc + k0 + 8);
            float4 y3 = *(const float4*)(bsrc + k0 + 12);

            step(buf);

            *(bf16x8*)(&Bs[buf ^ 1][brow][bhalf * 16])     = pack8(y0, y1);
            *(bf16x8*)(&Bs[buf ^ 1][brow][bhalf * 16 + 8]) = pack8(y2, y3);
            __syncthreads();
            buf ^= 1;
        }
        step(buf);                    // k0 = 992 (buf == 1)

        // LoRA-B ext: 2 K-steps over 64-wide slot space; es -> buffer es
        #pragma unroll
        for (int es = 0; es < 2; ++es) {
            GLOAD_LDS16(aesrc + es * 32, (char*)&As[es][0][0] + (wave * 64) * 16);
            #pragma unroll
            for (int r = 0; r < 2; ++r)
                GLOAD_LDS16(besrc[r] + es * 32, (char*)&Bs[es][0][0] + (r * 256 + wave * 64) * 16);
            __syncthreads();
            step(es);
        }

        // epilogue: fused silu_and_mul -> act bf16
        const int rb = wr * 32 + (lane >> 4) * 4;
        #pragma unroll
        for (int mi = 0; mi < 2; ++mi) {
            #pragma unroll
            for (int j = 0; j < 4; ++j) {
                int sidx = m0 + rb + mi * 16 + j;
                if (sidx < mend) {
                    int p = sorted[sidx];
                    ushort* ar = act + (size_t)p * 1024 + n0 + wc * 32;
                    #pragma unroll
                    for (int ni = 0; ni < 2; ++ni) {
                        float g = ag[mi][ni][j], u = au[mi][ni][j];
                        float v = g / (1.f + __expf(-g)) * u;
                        ar[ni * 16 + fr] = f2bf(v);
                    }
                }
            }
        }
        __syncthreads();
    }
}

// ---------------- down GEMM (R11): BM=64, BN=64, all-bf16 single-buffer, atomic weighted moe_sum ----------------
__global__ __launch_bounds__(256) void k_gemm_dn(
    const ushort* __restrict__ act, const ushort* __restrict__ w2b,
    const ushort* __restrict__ tmpde, const ushort* __restrict__ dbbe,
    const float* __restrict__ tw, float* __restrict__ out,
    const int* __restrict__ sorted, const int* __restrict__ offs)
{
    __shared__ ushort As[64][32];
    __shared__ ushort Bs[64][32];
    const int tid = threadIdx.x, lane = tid & 63, wave = tid >> 6;
    const int wr = wave >> 1, wc = wave & 1;
    const int fr = lane & 15, fk = (lane >> 4) * 8;

    int off[Ed + 1];
    #pragma unroll
    for (int e = 0; e <= Ed; ++e) off[e] = offs[e];
    int mt[Ed]; int tot = 0;
    #pragma unroll
    for (int e = 0; e < Ed; ++e) {
        mt[e] = (off[e + 1] - off[e] + 63) / 64;
        tot += mt[e] * 16;
    }

    for (int tau = blockIdx.x; tau < tot; tau += gridDim.x) {
        int t = tau, e = 0;
        while (t >= mt[e] * 16) { t -= mt[e] * 16; ++e; }
        const int m0 = off[e] + (t >> 4) * 64;
        const int mend = off[e + 1];
        const int n0 = (t & 15) * 64;

        const ushort *asrc, *aesrc, *bsrc, *besrc;
        {
            int aIdx = m0 + (tid >> 2); if (aIdx > mend - 1) aIdx = mend - 1;
            int p = sorted[aIdx];
            asrc  = act + (size_t)p * 1024 + (tid & 3) * 8;
            aesrc = tmpde + (size_t)p * 64 + (tid & 3) * 8;
            int row = tid >> 2, kc = tid & 3;
            bsrc  = w2b + ((size_t)e * Hd + n0 + row) * 1024 + kc * 8;
            besrc = dbbe + ((size_t)e * Hd + n0 + row) * 64 + kc * 8;
        }

        f32x4 acc[2][2] = {};
        auto step = [&]() {
            bf16x8 af[2], bv[2];
            #pragma unroll
            for (int mi = 0; mi < 2; ++mi)
                af[mi] = *(const bf16x8*)(&As[wr * 32 + mi * 16 + fr][fk]);
            #pragma unroll
            for (int ni = 0; ni < 2; ++ni)
                bv[ni] = *(const bf16x8*)(&Bs[wc * 32 + ni * 16 + fr][fk]);
            #pragma unroll
            for (int mi = 0; mi < 2; ++mi)
                #pragma unroll
                for (int ni = 0; ni < 2; ++ni)
                    acc[mi][ni] = __builtin_amdgcn_mfma_f32_16x16x32_bf16(af[mi], bv[ni], acc[mi][ni], 0, 0, 0);
        };

        for (int k0 = 0; k0 < 1024; k0 += 32) {
            GLOAD_LDS16(asrc + k0, (char*)&As[0][0] + (wave * 64) * 16);
            GLOAD_LDS16(bsrc + k0, (char*)&Bs[0][0] + (wave * 64) * 16);
            __syncthreads();
            step();
            __syncthreads();
        }
        #pragma unroll
        for (int es = 0; es < 2; ++es) {
            GLOAD_LDS16(aesrc + es * 32, (char*)&As[0][0] + (wave * 64) * 16);
            GLOAD_LDS16(besrc + es * 32, (char*)&Bs[0][0] + (wave * 64) * 16);
            __syncthreads();
            step();
            __syncthreads();
        }

        const int rb = wr * 32 + (lane >> 4) * 4;
        #pragma unroll
        for (int mi = 0; mi < 2; ++mi) {
            #pragma unroll
            for (int j = 0; j < 4; ++j) {
                int sidx = m0 + rb + mi * 16 + j;
                if (sidx < mend) {
                    int p = sorted[sidx];
                    float w = tw[p];
                    float* orow = out + (size_t)(p >> 1) * 1024 + n0 + wc * 32;
                    #pragma unroll
                    for (int ni = 0; ni < 2; ++ni)
                        atomicAdd(&orow[ni * 16 + fr], w * acc[mi][ni][j]);
                }
            }
        }
    }
}

extern "C" void kernel_launch(void* const* d_in, const int* in_sizes, int n_in,
                              void* d_out, int out_size, void* d_ws, size_t ws_size,
                              hipStream_t stream) {
    const float* hid  = (const float*)d_in[0];
    const float* tw   = (const float*)d_in[1];
    const float* w13  = (const float*)d_in[2];
    const float* w2   = (const float*)d_in[3];
    const float* ga   = (const float*)d_in[4];
    const float* gb   = (const float*)d_in[5];
    const float* da   = (const float*)d_in[6];
    const float* db   = (const float*)d_in[7];
    const float* sc   = (const float*)d_in[8];
    const int*   tids = (const int*)d_in[9];
    const int*   lidx = (const int*)d_in[10];
    float* out = (float*)d_out;

    char* ws = (char*)d_ws;
    ushort* xb     = (ushort*)(ws);                          // 2 MB
    ushort* w2b    = (ushort*)(ws + (2ull  << 20));          // 16 MB
    ushort* gbbe   = (ushort*)(ws + (18ull << 20));          // 2 MB
    ushort* dbbe   = (ushort*)(ws + (20ull << 20));          // 1 MB
    ushort* tmp1e  = (ushort*)(ws + (21ull << 20));          // 256 KB
    ushort* tmpde  = (ushort*)(ws + (21ull << 20) + (256u << 10)); // 256 KB
    ushort* act    = (ushort*)(ws + (22ull << 20));          // 4 MB
    int*    sorted = (int*)(ws + (26ull << 20));             // 8 KB
    int*    offs   = (int*)(ws + (26ull << 20) + TKd * 4);   // 36 B

    k_prep<<<PREP_BLOCKS, 256, 0, stream>>>(hid, gb, db, ga, sc, tids, lidx,
                                            xb, gbbe, dbbe, tmp1e, out, sorted, offs);
    k_gemm_gu<<<GUB + W2C, 256, 0, stream>>>(xb, w13, tmp1e, gbbe, w2, w2b, act, sorted, offs);
    k_tmp_dn<<<TKd, 256, 0, stream>>>(act, da, sc, tids, lidx, tmpde);
    k_gemm_dn<<<1024, 256, 0, stream>>>(act, w2b, tmpde, dbbe, tw, out, sorted, offs);
}

// Round 15
// 89.092 us; speedup vs baseline: 1.2050x; 1.0081x over previous
//
#include <hip/hip_runtime.h>
#include <stdint.h>

#define Td 1024
#define Hd 1024
#define Id 1024
#define Ed 8
#define Kd 2
#define Ld 4
#define Rd 16
#define Nd 2048
#define TKd (Td*Kd)

typedef __bf16 bf16x8 __attribute__((ext_vector_type(8)));
typedef float f32x4 __attribute__((ext_vector_type(4)));

__device__ __forceinline__ ushort f2bf(float f) {
    uint32_t u = __builtin_bit_cast(uint32_t, f);
    return (ushort)((u + 0x7fffu + ((u >> 16) & 1u)) >> 16);
}
__device__ __forceinline__ float bf2f(ushort u) {
    uint32_t x = ((uint32_t)u) << 16;
    return __builtin_bit_cast(float, x);
}
__device__ __forceinline__ bf16x8 pack8(float4 a, float4 b) {
    bf16x8 r;
    r[0] = (__bf16)a.x; r[1] = (__bf16)a.y; r[2] = (__bf16)a.z; r[3] = (__bf16)a.w;
    r[4] = (__bf16)b.x; r[5] = (__bf16)b.y; r[6] = (__bf16)b.z; r[7] = (__bf16)b.w;
    return r;
}
// 16 consecutive fp32 -> 16 bf16
__device__ __forceinline__ void cvt16(const float* __restrict__ s, ushort* __restrict__ d) {
    float4 a0 = *(const float4*)(s);
    float4 a1 = *(const float4*)(s + 4);
    float4 a2 = *(const float4*)(s + 8);
    float4 a3 = *(const float4*)(s + 12);
    uint4 o0, o1;
    o0.x = (uint)f2bf(a0.x) | ((uint)f2bf(a0.y) << 16);
    o0.y = (uint)f2bf(a0.z) | ((uint)f2bf(a0.w) << 16);
    o0.z = (uint)f2bf(a1.x) | ((uint)f2bf(a1.y) << 16);
    o0.w = (uint)f2bf(a1.z) | ((uint)f2bf(a1.w) << 16);
    o1.x = (uint)f2bf(a2.x) | ((uint)f2bf(a2.y) << 16);
    o1.y = (uint)f2bf(a2.z) | ((uint)f2bf(a2.w) << 16);
    o1.z = (uint)f2bf(a3.x) | ((uint)f2bf(a3.y) << 16);
    o1.w = (uint)f2bf(a3.z) | ((uint)f2bf(a3.w) << 16);
    *(uint4*)(d) = o0;
    *(uint4*)(d + 8) = o1;
}

#define GLOAD_LDS16(g, l) __builtin_amdgcn_global_load_lds( \
    (const __attribute__((address_space(1))) uint32_t*)(const void*)(g), \
    (__attribute__((address_space(3))) uint32_t*)(void*)(l), 16, 0, 0)

// bijective XCD-chunk swizzle (m204): bid -> tau; consecutive tau land on one XCD
__device__ __forceinline__ int xcd_swz(int bid, int tot) {
    int q = tot >> 3, r = tot & 7;
    int x = bid & 7, i = bid >> 3;
    return (x < r) ? x * (q + 1) + i : r * (q + 1) + (x - r) * q + i;
}

// block-role partition of k_prep (w2 conversion rides inside k_gemm_gu)
#define TB 2048    // gate_up LoRA-A projection (one per pair)
#define XB 256     // x convert, 16 floats/thread
#define CB 384     // LoRA-B interleave (rows of 16)
#define ZB 1024    // out zeroing
#define PREP_BLOCKS (TB + XB + CB + ZB + 1)

__global__ __launch_bounds__(256) void k_prep(
    const float* __restrict__ hid,
    const float* __restrict__ gb, const float* __restrict__ db,
    const float* __restrict__ ga, const float* __restrict__ sc,
    const int* __restrict__ tids, const int* __restrict__ lidx,
    ushort* __restrict__ xb,
    ushort* __restrict__ gbbe, ushort* __restrict__ dbbe, ushort* __restrict__ tmp1e,
    float* __restrict__ out, int* __restrict__ sorted, int* __restrict__ offs)
{
    __shared__ float tr[Rd];
    __shared__ int cnt[Ed];
    __shared__ int cur[Ed];
    const int b = blockIdx.x, tid = threadIdx.x;

    if (b < TB) {
        // gate_up LoRA-A projection: tmp1e[p][l*16+r] = s*(Ag[l,e]@x[t])
        const int p = b;
        const int e = tids[p];
        const int l = lidx[p >> 1];
        const float s = sc[l];
        const int r = tid >> 4, q = tid & 15;
        const float* A = ga + (((size_t)l * Ed + e) * Rd + r) * 1024;
        const float* x = hid + (size_t)(p >> 1) * 1024;
        float sum = 0.f;
        #pragma unroll
        for (int i = 0; i < 16; ++i) {
            int h = q * 4 + 64 * i;
            float4 a = *(const float4*)(A + h);
            float4 v = *(const float4*)(x + h);
            sum += a.x * v.x + a.y * v.y + a.z * v.z + a.w * v.w;
        }
        sum += __shfl_xor(sum, 1); sum += __shfl_xor(sum, 2);
        sum += __shfl_xor(sum, 4); sum += __shfl_xor(sum, 8);
        if (q == 0) tr[r] = sum;
        __syncthreads();
        if (tid < 32) {
            int j0 = tid * 2;
            uint v = 0;
            if ((j0 >> 4) == l)
                v = (uint)f2bf(s * tr[j0 & 15]) | ((uint)f2bf(s * tr[(j0 + 1) & 15]) << 16);
            ((uint*)(tmp1e + (size_t)p * 64))[tid] = v;
        }
    } else if (b < TB + XB) {
        size_t off = ((size_t)(b - TB) * 256 + tid) * 16;
        cvt16(hid + off, xb + off);
    } else if (b < TB + XB + CB) {
        // LoRA-B l-interleave: gbbe[e][n][l*16+r] = gb[l][e][n][r] (same for db)
        constexpr int GR = Ld * Ed * Nd;
        int i = (b - TB - XB) * 256 + tid;
        const float* src; ushort* dst;
        if (i < GR) {
            int l = i >> 14, e = (i >> 11) & 7, n = i & 2047;
            src = gb + (size_t)i * 16;
            dst = gbbe + ((size_t)(e * Nd + n)) * 64 + l * 16;
        } else {
            int j = i - GR;
            int l = j >> 13, e = (j >> 10) & 7, n = j & 1023;
            src = db + (size_t)j * 16;
            dst = dbbe + ((size_t)(e * Id + n)) * 64 + l * 16;
        }
        cvt16(src, dst);
    } else if (b < TB + XB + CB + ZB) {
        int i = (b - TB - XB - CB) * 256 + tid;
        ((float4*)out)[i] = make_float4(0.f, 0.f, 0.f, 0.f);
    } else {
        // route sort (single block, 8 pairs/thread)
        if (tid < Ed) cnt[tid] = 0;
        __syncthreads();
        int el[8];
        #pragma unroll
        for (int i = 0; i < 8; ++i) {
            el[i] = tids[tid + i * 256];
            atomicAdd(&cnt[el[i]], 1);
        }
        __syncthreads();
        if (tid == 0) {
            int s = 0;
            for (int e = 0; e < Ed; ++e) { offs[e] = s; cur[e] = s; s += cnt[e]; }
            offs[Ed] = s;
        }
        __syncthreads();
        #pragma unroll
        for (int i = 0; i < 8; ++i) {
            int pos = atomicAdd(&cur[el[i]], 1);
            sorted[pos] = tid + i * 256;
        }
    }
}

// ---------------- down LoRA-A projection (act bf16 input) ----------------
__global__ __launch_bounds__(256) void k_tmp_dn(
    const ushort* __restrict__ act, const float* __restrict__ da,
    const float* __restrict__ sc, const int* __restrict__ tids,
    const int* __restrict__ lidx, ushort* __restrict__ tmpde)
{
    const int p = blockIdx.x;
    const int e = tids[p];
    const int l = lidx[p >> 1];
    const float s = sc[l];
    const int tid = threadIdx.x;
    const int r = tid >> 4, q = tid & 15;
    const float* A = da + (((size_t)l * Ed + e) * Rd + r) * 1024;
    const ushort* x = act + (size_t)p * 1024;
    float sum = 0.f;
    #pragma unroll
    for (int i = 0; i < 8; ++i) {
        int h = q * 8 + 128 * i;
        float4 a0 = *(const float4*)(A + h);
        float4 a1 = *(const float4*)(A + h + 4);
        ushort4 v0 = *(const ushort4*)(x + h);
        ushort4 v1 = *(const ushort4*)(x + h + 4);
        sum += a0.x * bf2f(v0.x) + a0.y * bf2f(v0.y) + a0.z * bf2f(v0.z) + a0.w * bf2f(v0.w)
             + a1.x * bf2f(v1.x) + a1.y * bf2f(v1.y) + a1.z * bf2f(v1.z) + a1.w * bf2f(v1.w);
    }
    sum += __shfl_xor(sum, 1); sum += __shfl_xor(sum, 2);
    sum += __shfl_xor(sum, 4); sum += __shfl_xor(sum, 8);
    __shared__ float tr[Rd];
    if (q == 0) tr[r] = sum;
    __syncthreads();
    if (tid < 32) {
        int j0 = tid * 2;
        uint v = 0;
        if ((j0 >> 4) == l)
            v = (uint)f2bf(s * tr[j0 & 15]) | ((uint)f2bf(s * tr[(j0 + 1) & 15]) << 16);
        ((uint*)(tmpde + (size_t)p * 64))[tid] = v;
    }
}

// ---------------- gate_up GEMM (R14 structure) + m-fastest decode + XCD swizzle ----------------
#define GUB 1024
#define W2C 2048

__global__ __launch_bounds__(256) void k_gemm_gu(
    const ushort* __restrict__ xb, const float* __restrict__ w13,
    const ushort* __restrict__ tmp1e, const ushort* __restrict__ gbbe,
    const float* __restrict__ w2, ushort* __restrict__ w2b,
    ushort* __restrict__ act, const int* __restrict__ sorted,
    const int* __restrict__ offs)
{
    __shared__ ushort As[2][64][32];
    __shared__ ushort Bs[2][128][32];
    const int tid = threadIdx.x;

    if (blockIdx.x >= GUB) {
        // rider: w2 fp32 -> bf16 (overlaps GEMM; consumed only by k_gemm_dn)
        size_t off = ((size_t)(blockIdx.x - GUB) * 256 + tid) * 16;
        cvt16(w2 + off, w2b + off);
        return;
    }

    const int lane = tid & 63, wave = tid >> 6;
    const int wr = wave >> 1, wc = wave & 1;
    const int fr = lane & 15, fk = (lane >> 4) * 8;

    int off[Ed + 1];
    #pragma unroll
    for (int e = 0; e <= Ed; ++e) off[e] = offs[e];
    int mt[Ed], pre[Ed + 1];
    pre[0] = 0;
    #pragma unroll
    for (int e = 0; e < Ed; ++e) {
        mt[e] = (off[e + 1] - off[e] + 63) / 64;
        pre[e + 1] = pre[e] + mt[e] * 16;
    }
    const int tot = pre[Ed];

    for (int bid = blockIdx.x; bid < tot; bid += GUB) {
        const int tau = xcd_swz(bid, tot);
        int e = 0;
        while (tau >= pre[e + 1]) ++e;
        int local = tau - pre[e];
        // m-fastest: consecutive tau share the same n-panel (B reuse in XCD L2)
        int nt = local / mt[e];
        int mtile = local - nt * mt[e];
        const int m0 = off[e] + mtile * 64;
        const int mend = off[e + 1];
        const int n0 = nt * 64;

        // A (bf16, 1 round): chunk tid -> row tid>>2, kchunk tid&3
        const ushort *asrc, *aesrc;
        {
            int aIdx = m0 + (tid >> 2); if (aIdx > mend - 1) aIdx = mend - 1;
            int p = sorted[aIdx];
            asrc  = xb + (size_t)(p >> 1) * 1024 + (tid & 3) * 8;
            aesrc = tmp1e + (size_t)p * 64 + (tid & 3) * 8;
        }
        // B fp32: brow = tid>>1 (gate 0-63 / up 64-127), 16 floats per thread
        const int brow = tid >> 1, bhalf = tid & 1;
        const int bg_row = (brow < 64) ? (n0 + brow) : (1024 + n0 + brow - 64);
        const float* bsrc = w13 + ((size_t)e * Nd + bg_row) * 1024 + bhalf * 16;
        // B-ext (bf16, 2 rounds): chunk c -> row c>>2, kchunk c&3
        const ushort* besrc[2];
        #pragma unroll
        for (int r = 0; r < 2; ++r) {
            int c = r * 256 + tid;
            int row = c >> 2, kc = c & 3;
            int grow = (row < 64) ? (n0 + row) : (1024 + n0 + row - 64);
            besrc[r] = gbbe + ((size_t)e * Nd + grow) * 64 + kc * 8;
        }

        f32x4 ag[2][2] = {}, au[2][2] = {};
        auto step = [&](int b) {
            bf16x8 af[2], bg[2], bu[2];
            #pragma unroll
            for (int mi = 0; mi < 2; ++mi)
                af[mi] = *(const bf16x8*)(&As[b][wr * 32 + mi * 16 + fr][fk]);
            #pragma unroll
            for (int ni = 0; ni < 2; ++ni) {
                bg[ni] = *(const bf16x8*)(&Bs[b][wc * 32 + ni * 16 + fr][fk]);
                bu[ni] = *(const bf16x8*)(&Bs[b][64 + wc * 32 + ni * 16 + fr][fk]);
            }
            #pragma unroll
            for (int mi = 0; mi < 2; ++mi)
                #pragma unroll
                for (int ni = 0; ni < 2; ++ni) {
                    ag[mi][ni] = __builtin_amdgcn_mfma_f32_16x16x32_bf16(af[mi], bg[ni], ag[mi][ni], 0, 0, 0);
                    au[mi][ni] = __builtin_amdgcn_mfma_f32_16x16x32_bf16(af[mi], bu[ni], au[mi][ni], 0, 0, 0);
                }
        };

        // prologue: stage k0=0 into buffer 0
        GLOAD_LDS16(asrc, (char*)&As[0][0][0] + (wave * 64) * 16);
        {
            float4 y0 = *(const float4*)(bsrc);
            float4 y1 = *(const float4*)(bsrc + 4);
            float4 y2 = *(const float4*)(bsrc + 8);
            float4 y3 = *(const float4*)(bsrc + 12);
            *(bf16x8*)(&Bs[0][brow][bhalf * 16])     = pack8(y0, y1);
            *(bf16x8*)(&Bs[0][brow][bhalf * 16 + 8]) = pack8(y2, y3);
        }
        __syncthreads();

        int buf = 0;
        for (int k0 = 32; k0 < 1024; k0 += 32) {
            // issue next-step loads first (hide under MFMA)
            GLOAD_LDS16(asrc + k0, (char*)&As[buf ^ 1][0][0] + (wave * 64) * 16);
            float4 y0 = *(const float4*)(bsrc + k0);
            float4 y1 = *(const float4*)(bsrc + k0 + 4);
            float4 y2 = *(const float4*)(bsrc + k0 + 8);
            float4 y3 = *(const float4*)(bsrc + k0 + 12);

            step(buf);

            *(bf16x8*)(&Bs[buf ^ 1][brow][bhalf * 16])     = pack8(y0, y1);
            *(bf16x8*)(&Bs[buf ^ 1][brow][bhalf * 16 + 8]) = pack8(y2, y3);
            __syncthreads();
            buf ^= 1;
        }
        step(buf);                    // k0 = 992 (buf == 1)

        // LoRA-B ext: 2 K-steps over 64-wide slot space; es -> buffer es
        #pragma unroll
        for (int es = 0; es < 2; ++es) {
            GLOAD_LDS16(aesrc + es * 32, (char*)&As[es][0][0] + (wave * 64) * 16);
            #pragma unroll
            for (int r = 0; r < 2; ++r)
                GLOAD_LDS16(besrc[r] + es * 32, (char*)&Bs[es][0][0] + (r * 256 + wave * 64) * 16);
            __syncthreads();
            step(es);
        }

        // epilogue: fused silu_and_mul -> act bf16
        const int rb = wr * 32 + (lane >> 4) * 4;
        #pragma unroll
        for (int mi = 0; mi < 2; ++mi) {
            #pragma unroll
            for (int j = 0; j < 4; ++j) {
                int sidx = m0 + rb + mi * 16 + j;
                if (sidx < mend) {
                    int p = sorted[sidx];
                    ushort* ar = act + (size_t)p * 1024 + n0 + wc * 32;
                    #pragma unroll
                    for (int ni = 0; ni < 2; ++ni) {
                        float g = ag[mi][ni][j], u = au[mi][ni][j];
                        float v = g / (1.f + __expf(-g)) * u;
                        ar[ni * 16 + fr] = f2bf(v);
                    }
                }
            }
        }
        __syncthreads();
    }
}

// ---------------- down GEMM (R14 structure) + m-fastest decode + XCD swizzle ----------------
__global__ __launch_bounds__(256) void k_gemm_dn(
    const ushort* __restrict__ act, const ushort* __restrict__ w2b,
    const ushort* __restrict__ tmpde, const ushort* __restrict__ dbbe,
    const float* __restrict__ tw, float* __restrict__ out,
    const int* __restrict__ sorted, const int* __restrict__ offs)
{
    __shared__ ushort As[64][32];
    __shared__ ushort Bs[64][32];
    const int tid = threadIdx.x, lane = tid & 63, wave = tid >> 6;
    const int wr = wave >> 1, wc = wave & 1;
    const int fr = lane & 15, fk = (lane >> 4) * 8;

    int off[Ed + 1];
    #pragma unroll
    for (int e = 0; e <= Ed; ++e) off[e] = offs[e];
    int mt[Ed], pre[Ed + 1];
    pre[0] = 0;
    #pragma unroll
    for (int e = 0; e < Ed; ++e) {
        mt[e] = (off[e + 1] - off[e] + 63) / 64;
        pre[e + 1] = pre[e] + mt[e] * 16;
    }
    const int tot = pre[Ed];

    for (int bid = blockIdx.x; bid < tot; bid += gridDim.x) {
        const int tau = xcd_swz(bid, tot);
        int e = 0;
        while (tau >= pre[e + 1]) ++e;
        int local = tau - pre[e];
        int nt = local / mt[e];
        int mtile = local - nt * mt[e];
        const int m0 = off[e] + mtile * 64;
        const int mend = off[e + 1];
        const int n0 = nt * 64;

        const ushort *asrc, *aesrc, *bsrc, *besrc;
        {
            int aIdx = m0 + (tid >> 2); if (aIdx > mend - 1) aIdx = mend - 1;
            int p = sorted[aIdx];
            asrc  = act + (size_t)p * 1024 + (tid & 3) * 8;
            aesrc = tmpde + (size_t)p * 64 + (tid & 3) * 8;
            int row = tid >> 2, kc = tid & 3;
            bsrc  = w2b + ((size_t)e * Hd + n0 + row) * 1024 + kc * 8;
            besrc = dbbe + ((size_t)e * Hd + n0 + row) * 64 + kc * 8;
        }

        f32x4 acc[2][2] = {};
        auto step = [&]() {
            bf16x8 af[2], bv[2];
            #pragma unroll
            for (int mi = 0; mi < 2; ++mi)
                af[mi] = *(const bf16x8*)(&As[wr * 32 + mi * 16 + fr][fk]);
            #pragma unroll
            for (int ni = 0; ni < 2; ++ni)
                bv[ni] = *(const bf16x8*)(&Bs[wc * 32 + ni * 16 + fr][fk]);
            #pragma unroll
            for (int mi = 0; mi < 2; ++mi)
                #pragma unroll
                for (int ni = 0; ni < 2; ++ni)
                    acc[mi][ni] = __builtin_amdgcn_mfma_f32_16x16x32_bf16(af[mi], bv[ni], acc[mi][ni], 0, 0, 0);
        };

        for (int k0 = 0; k0 < 1024; k0 += 32) {
            GLOAD_LDS16(asrc + k0, (char*)&As[0][0] + (wave * 64) * 16);
            GLOAD_LDS16(bsrc + k0, (char*)&Bs[0][0] + (wave * 64) * 16);
            __syncthreads();
            step();
            __syncthreads();
        }
        #pragma unroll
        for (int es = 0; es < 2; ++es) {
            GLOAD_LDS16(aesrc + es * 32, (char*)&As[0][0] + (wave * 64) * 16);
            GLOAD_LDS16(besrc + es * 32, (char*)&Bs[0][0] + (wave * 64) * 16);
            __syncthreads();
            step();
            __syncthreads();
        }

        const int rb = wr * 32 + (lane >> 4) * 4;
        #pragma unroll
        for (int mi = 0; mi < 2; ++mi) {
            #pragma unroll
            for (int j = 0; j < 4; ++j) {
                int sidx = m0 + rb + mi * 16 + j;
                if (sidx < mend) {
                    int p = sorted[sidx];
                    float w = tw[p];
                    float* orow = out + (size_t)(p >> 1) * 1024 + n0 + wc * 32;
                    #pragma unroll
                    for (int ni = 0; ni < 2; ++ni)
                        atomicAdd(&orow[ni * 16 + fr], w * acc[mi][ni][j]);
                }
            }
        }
    }
}

extern "C" void kernel_launch(void* const* d_in, const int* in_sizes, int n_in,
                              void* d_out, int out_size, void* d_ws, size_t ws_size,
                              hipStream_t stream) {
    const float* hid  = (const float*)d_in[0];
    const float* tw   = (const float*)d_in[1];
    const float* w13  = (const float*)d_in[2];
    const float* w2   = (const float*)d_in[3];
    const float* ga   = (const float*)d_in[4];
    const float* gb   = (const float*)d_in[5];
    const float* da   = (const float*)d_in[6];
    const float* db   = (const float*)d_in[7];
    const float* sc   = (const float*)d_in[8];
    const int*   tids = (const int*)d_in[9];
    const int*   lidx = (const int*)d_in[10];
    float* out = (float*)d_out;

    char* ws = (char*)d_ws;
    ushort* xb     = (ushort*)(ws);                          // 2 MB
    ushort* w2b    = (ushort*)(ws + (2ull  << 20));          // 16 MB
    ushort* gbbe   = (ushort*)(ws + (18ull << 20));          // 2 MB
    ushort* dbbe   = (ushort*)(ws + (20ull << 20));          // 1 MB
    ushort* tmp1e  = (ushort*)(ws + (21ull << 20));          // 256 KB
    ushort* tmpde  = (ushort*)(ws + (21ull << 20) + (256u << 10)); // 256 KB
    ushort* act    = (ushort*)(ws + (22ull << 20));          // 4 MB
    int*    sorted = (int*)(ws + (26ull << 20));             // 8 KB
    int*    offs   = (int*)(ws + (26ull << 20) + TKd * 4);   // 36 B

    k_prep<<<PREP_BLOCKS, 256, 0, stream>>>(hid, gb, db, ga, sc, tids, lidx,
                                            xb, gbbe, dbbe, tmp1e, out, sorted, offs);
    k_gemm_gu<<<GUB + W2C, 256, 0, stream>>>(xb, w13, tmp1e, gbbe, w2, w2b, act, sorted, offs);
    k_tmp_dn<<<TKd, 256, 0, stream>>>(act, da, sc, tids, lidx, tmpde);
    k_gemm_dn<<<1024, 256, 0, stream>>>(act, w2b, tmpde, dbbe, tw, out, sorted, offs);
}